// Round 10
// baseline (4750.365 us; speedup 1.0000x reference)
//
#include <hip/hip_runtime.h>
#include <hip/hip_fp16.h>
#include <vector>
#include <array>
#include <map>
#include <algorithm>

#define BATCH 32
#define NV    10242
#define NF    20480
#define NBB   64          // 2 hemis * 32 batches ; lane = bb
#define NSTEPS 10
#define STEPSZ 0.1f
#define EPSV   1e-8f
#define NCHUNK 16
#define CHSZ   641        // ceil(NV/NCHUNK)
#define NPAIR  5121       // NV/2 vertex pairs; one pair per wave

// ---------------- workspace layout: lane = bb ----------------
// v     : [NV][NBB] float4   (x, y, z, sulc)       -- NEW (BFS) id, f32
// featH : [NV][NBB] float4 = 8 x fp16 {nx,ny,nz, lx,ly,lz, 0,0}
// h     : [NV][2][NBB] float4 = 16 x fp16 channels
// fp16 is STORAGE ONLY; all accumulation f32 (round-8: __hadd2 accum failed gate).
static constexpr size_t OFF_V    = 0;                                  // floats
static constexpr size_t OFF_FEAT = OFF_V    + (size_t)NV * NBB * 4;
static constexpr size_t OFF_H    = OFF_FEAT + (size_t)NV * NBB * 4;
static constexpr size_t OFF_CSZ  = OFF_H    + (size_t)NV * NBB * 8;    // [6][NBB] ctr(3),size(3)
static constexpr size_t OFF_INT  = OFF_CSZ  + 6 * NBB;
// int region: deg @0  nbrB @NV..7NV  nbrC @7NV..13NV  newid @13NV  order @14NV [pad]
//   adjB8 @16NV..24NV : {b0..b5, deg, 0}   adjC8 @24NV..32NV : {c0..c5, 0, 0}

__device__ __forceinline__ int rfl(int x) { return __builtin_amdgcn_readfirstlane(x); }

union HF4 { float4 f4; __half2 h2[4]; };

__device__ __forceinline__ float4 pack8(const float* x) {
    HF4 u;
    u.h2[0] = __floats2half2_rn(x[0], x[1]);
    u.h2[1] = __floats2half2_rn(x[2], x[3]);
    u.h2[2] = __floats2half2_rn(x[4], x[5]);
    u.h2[3] = __floats2half2_rn(x[6], x[7]);
    return u.f4;
}
__device__ __forceinline__ void unpack8(float4 v, float* x) {
    HF4 u;
    u.f4 = v;
#pragma unroll
    for (int i = 0; i < 4; i++) {
        float2 f = __half22float2(u.h2[i]);
        x[2 * i] = f.x; x[2 * i + 1] = f.y;
    }
}

// bijective XCD chunking swizzle: contiguous NEW-id vertex range per XCD
__device__ __forceinline__ int swz(int b, int n) {
    int q = n >> 3, r = n & 7;
    int x = b & 7, i = b >> 3;
    return (x < r ? x * (q + 1) : r * (q + 1) + (x - r) * q) + i;
}

// ================= host-side BFS permutation (once per process) =================
static int g_order[NV], g_newid[NV];
static bool g_perm_built = false;

static void build_perm_host() {
    if (g_perm_built) return;
    int nv = 12;
    std::vector<std::array<int, 3>> f = {
        {0,11,5},{0,5,1},{0,1,7},{0,7,10},{0,10,11},
        {1,5,9},{5,11,4},{11,10,2},{10,7,6},{7,1,8},
        {3,9,4},{3,4,2},{3,2,6},{3,6,8},{3,8,9},
        {4,9,5},{2,4,11},{6,2,10},{8,6,7},{9,8,1}};
    for (int s = 0; s < 5; s++) {
        std::map<long long, int> cache;
        auto mid = [&](int a, int b) {
            long long key = (long long)std::min(a, b) * 1000000LL + std::max(a, b);
            auto it = cache.find(key);
            if (it != cache.end()) return it->second;
            int idx = nv++;
            cache.emplace(key, idx);
            return idx;
        };
        std::vector<std::array<int, 3>> nf;
        nf.reserve(f.size() * 4);
        for (auto& fc : f) {
            int a = fc[0], b = fc[1], c = fc[2];
            int ab = mid(a, b), bc = mid(b, c), ca = mid(c, a);
            nf.push_back({a, ab, ca}); nf.push_back({b, bc, ab});
            nf.push_back({c, ca, bc}); nf.push_back({ab, bc, ca});
        }
        f.swap(nf);
    }
    std::vector<std::array<int, 6>> nbr(NV);
    std::vector<int> deg(NV, 0);
    for (auto& fc : f)
        for (int c = 0; c < 3; c++) {
            int vtx = fc[c];
            if (vtx < NV && deg[vtx] < 6) nbr[vtx][deg[vtx]++] = fc[(c + 1) % 3];
        }
    std::vector<int> vis(NV, -1);
    int tail = 0;
    g_order[tail] = 0; vis[0] = tail; tail++;
    for (int head = 0; head < tail; head++) {
        int u = g_order[head];
        for (int k = 0; k < deg[u]; k++) {
            int w = nbr[u][k];
            if (vis[w] < 0) { vis[w] = tail; g_order[tail++] = w; }
        }
    }
    for (int i = 0; i < NV; i++)
        if (vis[i] < 0) { vis[i] = tail; g_order[tail++] = i; }
    for (int i = 0; i < NV; i++) g_newid[i] = vis[i];
    g_perm_built = true;
}

// ---------------- adjacency build (once per launch) ----------------
__global__ __launch_bounds__(256) void k_zero(int* p, int n) {
    int i = blockIdx.x * 256 + threadIdx.x;
    if (i < n) p[i] = 0;
}

__global__ __launch_bounds__(256) void k_build(const int* __restrict__ faces,
                                               int* deg, int* nbrB, int* nbrC) {
    int fi = blockIdx.x * 256 + threadIdx.x;
    if (fi >= NF) return;
    int vv[3] = {faces[fi * 3 + 0], faces[fi * 3 + 1], faces[fi * 3 + 2]};
#pragma unroll
    for (int c = 0; c < 3; c++) {
        int vtx = vv[c];
        int s = atomicAdd(&deg[vtx], 1);
        nbrB[vtx * 6 + s] = vv[(c + 1) % 3];   // next corner = dedup'd neighbor
        nbrC[vtx * 6 + s] = vv[(c + 2) % 3];   // prev corner
    }
}

// ---------------- remap adjacency to new ids, packed 8-int rows ----------------
__global__ __launch_bounds__(256) void k_remap(const int* __restrict__ deg,
                                               const int* __restrict__ nbrB,
                                               const int* __restrict__ nbrC,
                                               const int* __restrict__ newid,
                                               const int* __restrict__ order,
                                               int* __restrict__ adjB8,
                                               int* __restrict__ adjC8) {
    int n = blockIdx.x * 256 + threadIdx.x;
    if (n >= NV) return;
    int o = order[n];
    int d = deg[o];
    int b[8], c[8];
#pragma unroll
    for (int k = 0; k < 6; k++) {
        b[k] = (k < d) ? newid[nbrB[o * 6 + k]] : 0;
        c[k] = (k < d) ? newid[nbrC[o * 6 + k]] : 0;
    }
    b[6] = d; b[7] = 0; c[6] = 0; c[7] = 0;
#pragma unroll
    for (int k = 0; k < 8; k++) { adjB8[n * 8 + k] = b[k]; adjC8[n * 8 + k] = c[k]; }
}

// ---------------- bbox phase 1: per-(chunk,bb) partial min/max ----------------
__global__ __launch_bounds__(256) void k_bbox1(const float* __restrict__ lh,
                                               const float* __restrict__ rh,
                                               float* __restrict__ part) {
    int ch = blockIdx.x, bb = blockIdx.y;
    const float* src = (bb < BATCH) ? (lh + (size_t)bb * NV * 3)
                                    : (rh + (size_t)(bb - BATCH) * NV * 3);
    int lo = ch * CHSZ, hi = min(lo + CHSZ, NV);
    __shared__ float smin[3][256], smax[3][256];
    float mn[3] = {1e30f, 1e30f, 1e30f}, mx[3] = {-1e30f, -1e30f, -1e30f};
    for (int i = lo + threadIdx.x; i < hi; i += 256) {
#pragma unroll
        for (int c = 0; c < 3; c++) {
            float x = src[i * 3 + c];
            mn[c] = fminf(mn[c], x);
            mx[c] = fmaxf(mx[c], x);
        }
    }
#pragma unroll
    for (int c = 0; c < 3; c++) { smin[c][threadIdx.x] = mn[c]; smax[c][threadIdx.x] = mx[c]; }
    __syncthreads();
    for (int s = 128; s > 0; s >>= 1) {
        if (threadIdx.x < s) {
#pragma unroll
            for (int c = 0; c < 3; c++) {
                smin[c][threadIdx.x] = fminf(smin[c][threadIdx.x], smin[c][threadIdx.x + s]);
                smax[c][threadIdx.x] = fmaxf(smax[c][threadIdx.x], smax[c][threadIdx.x + s]);
            }
        }
        __syncthreads();
    }
    if (threadIdx.x == 0) {
        float* p = part + ((size_t)ch * NBB + bb) * 6;
#pragma unroll
        for (int c = 0; c < 3; c++) { p[c] = smin[c][0]; p[3 + c] = smax[c][0]; }
    }
}

// ---------------- bbox phase 2: combine -> csz ----------------
__global__ __launch_bounds__(64) void k_bbox2(const float* __restrict__ part,
                                              float* __restrict__ csz) {
    int bb = threadIdx.x;
    float mn[3] = {1e30f, 1e30f, 1e30f}, mx[3] = {-1e30f, -1e30f, -1e30f};
    for (int ch = 0; ch < NCHUNK; ch++) {
        const float* p = part + ((size_t)ch * NBB + bb) * 6;
#pragma unroll
        for (int c = 0; c < 3; c++) {
            mn[c] = fminf(mn[c], p[c]);
            mx[c] = fmaxf(mx[c], p[3 + c]);
        }
    }
#pragma unroll
    for (int c = 0; c < 3; c++) {
        float ctr = 0.5f * (mn[c] + mx[c]);
        csz[c * NBB + bb] = ctr;
        csz[(3 + c) * NBB + bb] = mx[c] - ctr;
    }
}

// ---------------- normalize + transpose-in, scattered to NEW ids ----------------
__global__ __launch_bounds__(256) void k_normT(const float* __restrict__ lh,
                                               const float* __restrict__ rh,
                                               const float* __restrict__ csz,
                                               const int* __restrict__ newid,
                                               float4* __restrict__ v4) {
    int ch = blockIdx.x, bb = blockIdx.y;
    const float* src = (bb < BATCH) ? (lh + (size_t)bb * NV * 3)
                                    : (rh + (size_t)(bb - BATCH) * NV * 3);
    float ctr[3], isz[3];
#pragma unroll
    for (int c = 0; c < 3; c++) {
        ctr[c] = csz[c * NBB + bb];
        isz[c] = 1.f / csz[(3 + c) * NBB + bb];
    }
    int lo = ch * CHSZ, hi = min(lo + CHSZ, NV);
    for (int i = lo + threadIdx.x; i < hi; i += 256) {
        float4 o;
        o.x = (src[i * 3 + 0] - ctr[0]) * isz[0];
        o.y = (src[i * 3 + 1] - ctr[1]) * isz[1];
        o.z = (src[i * 3 + 2] - ctr[2]) * isz[2];
        o.w = 0.f;                               // sulc lives in v.w
        v4[(size_t)newid[i] * NBB + bb] = o;
    }
}

// ================= per-step loop kernels: ONE VERTEX PAIR PER WAVE =================
// Pipeline: issue A gathers -> issue B own -> accumulate A -> issue B gathers ->
// compute/store A (B loads in flight under A's VALU) -> compute/store B.
// Per-vertex accumulation order identical to round-9 (bit-identical numerics).

// ---------------- geometry -> featH = fp16x8 {n, 0.5*lap} ----------------
__global__ __launch_bounds__(256) void k_geom(const float4* __restrict__ v4,
                                              const int* __restrict__ adjB8,
                                              const int* __restrict__ adjC8,
                                              float4* __restrict__ featH) {
    int t = threadIdx.x;
    int lane = t & 63;
    int w = rfl(swz(blockIdx.x, gridDim.x) * 4 + (t >> 6));
    if (w >= NPAIR) return;
    int vA = 2 * w, vB = vA + 1;               // NV even -> vB always valid
    float sgn = (lane < BATCH) ? 1.f : -1.f;   // rh: reversed winding flips face normals

    auto acc1 = [&](float4 a, float4 b, float4 c, float* vn, float* l) {
        float e1x = b.x - a.x, e1y = b.y - a.y, e1z = b.z - a.z;   // B - A
        float e2x = c.x - a.x, e2y = c.y - a.y, e2z = c.z - a.z;   // C - A
        float fnx = e1y * e2z - e1z * e2y;
        float fny = e1z * e2x - e1x * e2z;
        float fnz = e1x * e2y - e1y * e2x;
        vn[0] += fnx; vn[1] += fny; vn[2] += fnz;
        float rd = 1.f / (sqrtf(fnx * fnx + fny * fny + fnz * fnz) + EPSV);
        float ux = c.x - b.x, uy = c.y - b.y, uz = c.z - b.z;
        float wx = a.x - b.x, wy = a.y - b.y, wz = a.z - b.z;
        float cB = (ux * wx + uy * wy + uz * wz) * rd;             // cot at B
        float rx = a.x - c.x, ry = a.y - c.y, rz = a.z - c.z;
        float sx = b.x - c.x, sy = b.y - c.y, sz2 = b.z - c.z;
        float cC = (rx * sx + ry * sy + rz * sz2) * rd;            // cot at C
        l[0] += cC * e1x + cB * e2x;
        l[1] += cC * e1y + cB * e2y;
        l[2] += cC * e1z + cB * e2z;
    };
    auto finish = [&](int vi, const float* vn, const float* l) {
        float nn = 1.f / (sqrtf(vn[0]*vn[0] + vn[1]*vn[1] + vn[2]*vn[2]) + EPSV);
        float nl[8] = {vn[0]*nn, vn[1]*nn, vn[2]*nn, 0.5f*l[0], 0.5f*l[1], 0.5f*l[2], 0.f, 0.f};
        featH[(size_t)vi * NBB + lane] = pack8(nl);
    };
    auto serial = [&](int vi, const int* ib, const int* ic, int d) {
        float4 a = v4[(size_t)vi * NBB + lane];
        float vn[3] = {0.f, 0.f, 0.f}, l[3] = {0.f, 0.f, 0.f};
#pragma unroll
        for (int k = 0; k < 6; k++)
            if (k < d) acc1(a, v4[(size_t)ib[k] * NBB + lane],
                               v4[(size_t)ic[k] * NBB + lane], vn, l);
        vn[0] *= sgn; vn[1] *= sgn; vn[2] *= sgn;
        finish(vi, vn, l);
    };

    int4 ablo = *(const int4*)&adjB8[(size_t)vA * 8];
    int4 abhi = *(const int4*)&adjB8[(size_t)vA * 8 + 4];
    int4 aclo = *(const int4*)&adjC8[(size_t)vA * 8];
    int4 achi = *(const int4*)&adjC8[(size_t)vA * 8 + 4];
    int4 bblo = *(const int4*)&adjB8[(size_t)vB * 8];
    int4 bbhi = *(const int4*)&adjB8[(size_t)vB * 8 + 4];
    int4 bclo = *(const int4*)&adjC8[(size_t)vB * 8];
    int4 bchi = *(const int4*)&adjC8[(size_t)vB * 8 + 4];
    int dA = rfl(abhi.z), dB = rfl(bbhi.z);
    int ibA[6] = {rfl(ablo.x), rfl(ablo.y), rfl(ablo.z), rfl(ablo.w), rfl(abhi.x), rfl(abhi.y)};
    int icA[6] = {rfl(aclo.x), rfl(aclo.y), rfl(aclo.z), rfl(aclo.w), rfl(achi.x), rfl(achi.y)};
    int ibB[6] = {rfl(bblo.x), rfl(bblo.y), rfl(bblo.z), rfl(bblo.w), rfl(bbhi.x), rfl(bbhi.y)};
    int icB[6] = {rfl(bclo.x), rfl(bclo.y), rfl(bclo.z), rfl(bclo.w), rfl(bchi.x), rfl(bchi.y)};

    if (dA == 6 && dB == 6) {
        float4 aA = v4[(size_t)vA * NBB + lane];
        float4 pbA[6], pcA[6];
#pragma unroll
        for (int k = 0; k < 6; k++) {
            pbA[k] = v4[(size_t)ibA[k] * NBB + lane];
            pcA[k] = v4[(size_t)icA[k] * NBB + lane];
        }
        float4 aB = v4[(size_t)vB * NBB + lane];
        float4 pbB[6], pcB[6];
#pragma unroll
        for (int k = 0; k < 6; k++) {          // B gathers in flight during A compute
            pbB[k] = v4[(size_t)ibB[k] * NBB + lane];
            pcB[k] = v4[(size_t)icB[k] * NBB + lane];
        }
        float vnA[3] = {0.f, 0.f, 0.f}, lA[3] = {0.f, 0.f, 0.f};
#pragma unroll
        for (int k = 0; k < 6; k++) acc1(aA, pbA[k], pcA[k], vnA, lA);
        vnA[0] *= sgn; vnA[1] *= sgn; vnA[2] *= sgn;
        finish(vA, vnA, lA);
        float vnB[3] = {0.f, 0.f, 0.f}, lB[3] = {0.f, 0.f, 0.f};
#pragma unroll
        for (int k = 0; k < 6; k++) acc1(aB, pbB[k], pcB[k], vnB, lB);
        vnB[0] *= sgn; vnB[1] *= sgn; vnB[2] *= sgn;
        finish(vB, vnB, lB);
    } else {
        serial(vA, ibA, icA, dA);
        serial(vB, ibB, icB, dB);
    }
}

// ---------------- layer1  h = relu(feat@W1s + mean_nbr(feat)@W1n + b1) ----------------
__global__ __launch_bounds__(256) void k_layer1(const float4* __restrict__ v4,
                                                const float4* __restrict__ featH,
                                                const int* __restrict__ adjB8,
                                                const float* __restrict__ W1s,
                                                const float* __restrict__ W1n,
                                                const float* __restrict__ b1,
                                                float4* __restrict__ h4) {
    __shared__ float sWs[144], sWn[144], sb[16];
    int t = threadIdx.x;
    if (t < 144) { sWs[t] = W1s[t]; sWn[t] = W1n[t]; }
    if (t < 16) sb[t] = b1[t];
    __syncthreads();
    int lane = t & 63;
    int w = rfl(swz(blockIdx.x, gridDim.x) * 4 + (t >> 6));
    if (w >= NPAIR) return;
    int vA = 2 * w, vB = vA + 1;

    auto gemm_store = [&](int vi, float4 ov, float4 onl, float* m) {
        float nl[8];
        unpack8(onl, nl);
        float own[9] = {ov.x, ov.y, ov.z, nl[0], nl[1], nl[2], nl[3], nl[4], nl[5]};
        float inv = 1.f / 6.f;   // overwritten by caller for d!=6 via m pre-scale
#pragma unroll
        for (int i = 0; i < 9; i++) m[i] *= inv;
        HF4 h0, h1;
#pragma unroll
        for (int jp = 0; jp < 8; jp++) {
            float a0 = sb[2 * jp], a1 = sb[2 * jp + 1];
#pragma unroll
            for (int i = 0; i < 9; i++) {
                a0 += own[i] * sWs[i * 16 + 2 * jp]     + m[i] * sWn[i * 16 + 2 * jp];
                a1 += own[i] * sWs[i * 16 + 2 * jp + 1] + m[i] * sWn[i * 16 + 2 * jp + 1];
            }
            __half2 p = __floats2half2_rn(fmaxf(a0, 0.f), fmaxf(a1, 0.f));
            if (jp < 4) h0.h2[jp] = p; else h1.h2[jp - 4] = p;
        }
        float4* hp = h4 + (size_t)vi * 2 * NBB + lane;
        hp[0 * NBB] = h0.f4;
        hp[1 * NBB] = h1.f4;
    };
    auto gemm_store_d = [&](int vi, float4 ov, float4 onl, float* m, int d) {
        float nl[8];
        unpack8(onl, nl);
        float own[9] = {ov.x, ov.y, ov.z, nl[0], nl[1], nl[2], nl[3], nl[4], nl[5]};
        float inv = 1.f / (float)d;
#pragma unroll
        for (int i = 0; i < 9; i++) m[i] *= inv;
        HF4 h0, h1;
#pragma unroll
        for (int jp = 0; jp < 8; jp++) {
            float a0 = sb[2 * jp], a1 = sb[2 * jp + 1];
#pragma unroll
            for (int i = 0; i < 9; i++) {
                a0 += own[i] * sWs[i * 16 + 2 * jp]     + m[i] * sWn[i * 16 + 2 * jp];
                a1 += own[i] * sWs[i * 16 + 2 * jp + 1] + m[i] * sWn[i * 16 + 2 * jp + 1];
            }
            __half2 p = __floats2half2_rn(fmaxf(a0, 0.f), fmaxf(a1, 0.f));
            if (jp < 4) h0.h2[jp] = p; else h1.h2[jp - 4] = p;
        }
        float4* hp = h4 + (size_t)vi * 2 * NBB + lane;
        hp[0 * NBB] = h0.f4;
        hp[1 * NBB] = h1.f4;
    };

    int4 alo = *(const int4*)&adjB8[(size_t)vA * 8];
    int4 ahi = *(const int4*)&adjB8[(size_t)vA * 8 + 4];
    int4 blo = *(const int4*)&adjB8[(size_t)vB * 8];
    int4 bhi = *(const int4*)&adjB8[(size_t)vB * 8 + 4];
    int dA = rfl(ahi.z), dB = rfl(bhi.z);
    int ibA[6] = {rfl(alo.x), rfl(alo.y), rfl(alo.z), rfl(alo.w), rfl(ahi.x), rfl(ahi.y)};
    int ibB[6] = {rfl(blo.x), rfl(blo.y), rfl(blo.z), rfl(blo.w), rfl(bhi.x), rfl(bhi.y)};

    if (dA == 6 && dB == 6) {
        // A own + gathers
        float4 ovA  = v4[(size_t)vA * NBB + lane];
        float4 onlA = featH[(size_t)vA * NBB + lane];
        float4 gvA[6], gnA[6];
#pragma unroll
        for (int k = 0; k < 6; k++) {
            gvA[k] = v4[(size_t)ibA[k] * NBB + lane];
            gnA[k] = featH[(size_t)ibA[k] * NBB + lane];
        }
        // B own issued early
        float4 ovB  = v4[(size_t)vB * NBB + lane];
        float4 onlB = featH[(size_t)vB * NBB + lane];
        // accumulate A (order identical to round 9: k = 0..5)
        float mA[9] = {0.f, 0.f, 0.f, 0.f, 0.f, 0.f, 0.f, 0.f, 0.f};
        float nl[8];
#pragma unroll
        for (int k = 0; k < 6; k++) {
            mA[0] += gvA[k].x; mA[1] += gvA[k].y; mA[2] += gvA[k].z;
            unpack8(gnA[k], nl);
            mA[3] += nl[0]; mA[4] += nl[1]; mA[5] += nl[2];
            mA[6] += nl[3]; mA[7] += nl[4]; mA[8] += nl[5];
        }
        // B gathers in flight during A GEMM
        float4 gvB[6], gnB[6];
#pragma unroll
        for (int k = 0; k < 6; k++) {
            gvB[k] = v4[(size_t)ibB[k] * NBB + lane];
            gnB[k] = featH[(size_t)ibB[k] * NBB + lane];
        }
        gemm_store(vA, ovA, onlA, mA);
        float mB[9] = {0.f, 0.f, 0.f, 0.f, 0.f, 0.f, 0.f, 0.f, 0.f};
#pragma unroll
        for (int k = 0; k < 6; k++) {
            mB[0] += gvB[k].x; mB[1] += gvB[k].y; mB[2] += gvB[k].z;
            unpack8(gnB[k], nl);
            mB[3] += nl[0]; mB[4] += nl[1]; mB[5] += nl[2];
            mB[6] += nl[3]; mB[7] += nl[4]; mB[8] += nl[5];
        }
        gemm_store(vB, ovB, onlB, mB);
    } else {
#pragma unroll 1
        for (int s = 0; s < 2; s++) {
            int vi = (s == 0) ? vA : vB;
            const int* ib = (s == 0) ? ibA : ibB;
            int d = (s == 0) ? dA : dB;
            float4 ov  = v4[(size_t)vi * NBB + lane];
            float4 onl = featH[(size_t)vi * NBB + lane];
            float m[9] = {0.f, 0.f, 0.f, 0.f, 0.f, 0.f, 0.f, 0.f, 0.f};
            float nl[8];
#pragma unroll
            for (int k = 0; k < 6; k++)
                if (k < d) {
                    float4 gv = v4[(size_t)ib[k] * NBB + lane];
                    float4 gn = featH[(size_t)ib[k] * NBB + lane];
                    m[0] += gv.x; m[1] += gv.y; m[2] += gv.z;
                    unpack8(gn, nl);
                    m[3] += nl[0]; m[4] += nl[1]; m[5] += nl[2];
                    m[6] += nl[3]; m[7] += nl[4]; m[8] += nl[5];
                }
            gemm_store_d(vi, ov, onl, m, d);
        }
    }
}

// ---------------- layer2 + output head + state update (sulc in v.w) ----------------
__global__ __launch_bounds__(256) void k_layer2(const float4* __restrict__ h4,
                                                const float4* __restrict__ featH,
                                                const int* __restrict__ adjB8,
                                                const float* __restrict__ W2s,
                                                const float* __restrict__ W2n,
                                                const float* __restrict__ b2,
                                                const float* __restrict__ Wo,
                                                const float* __restrict__ bo,
                                                float4* __restrict__ v4) {
    __shared__ float sWs[256], sWn[256], sb[16], sWo[48], sbo[3];
    int t = threadIdx.x;
    sWs[t] = W2s[t];
    sWn[t] = W2n[t];
    if (t < 16) sb[t] = b2[t];
    if (t < 48) sWo[t] = Wo[t];
    if (t < 3) sbo[t] = bo[t];
    __syncthreads();
    int lane = t & 63;
    int w = rfl(swz(blockIdx.x, gridDim.x) * 4 + (t >> 6));
    if (w >= NPAIR) return;
    int vA = 2 * w, vB = vA + 1;

    auto gemm_store = [&](int vi, float4 fnl, float4 vv, float4 o0, float4 o1,
                          float* m, int d) {
        float own[16];
        unpack8(o0, own); unpack8(o1, own + 8);
        float inv = 1.f / (float)d;
#pragma unroll
        for (int i = 0; i < 16; i++) m[i] *= inv;
        float dv[3] = {sbo[0], sbo[1], sbo[2]};
#pragma unroll
        for (int j = 0; j < 16; j++) {       // output head folded in
            float acc = sb[j];
#pragma unroll
            for (int i = 0; i < 16; i++) acc += own[i] * sWs[i * 16 + j] + m[i] * sWn[i * 16 + j];
            acc = fmaxf(acc, 0.f);
            dv[0] += acc * sWo[j * 3 + 0];
            dv[1] += acc * sWo[j * 3 + 1];
            dv[2] += acc * sWo[j * 3 + 2];
        }
        float nlo[8];
        unpack8(fnl, nlo);
        vv.x += STEPSZ * dv[0];
        vv.y += STEPSZ * dv[1];
        vv.z += STEPSZ * dv[2];
        vv.w += STEPSZ * (nlo[0] * dv[0] + nlo[1] * dv[1] + nlo[2] * dv[2]);
        v4[(size_t)vi * NBB + lane] = vv;
    };

    int4 alo = *(const int4*)&adjB8[(size_t)vA * 8];
    int4 ahi = *(const int4*)&adjB8[(size_t)vA * 8 + 4];
    int4 blo = *(const int4*)&adjB8[(size_t)vB * 8];
    int4 bhi = *(const int4*)&adjB8[(size_t)vB * 8 + 4];
    int dA = rfl(ahi.z), dB = rfl(bhi.z);
    int ibA[6] = {rfl(alo.x), rfl(alo.y), rfl(alo.z), rfl(alo.w), rfl(ahi.x), rfl(ahi.y)};
    int ibB[6] = {rfl(blo.x), rfl(blo.y), rfl(blo.z), rfl(blo.w), rfl(bhi.x), rfl(bhi.y)};

    if (dA == 6 && dB == 6) {
        // A own + gathers
        float4 fnlA = featH[(size_t)vA * NBB + lane];
        float4 vvA  = v4[(size_t)vA * NBB + lane];
        const float4* hoA = h4 + (size_t)vA * 2 * NBB + lane;
        float4 oA0 = hoA[0 * NBB], oA1 = hoA[1 * NBB];
        float4 gA[12];
#pragma unroll
        for (int k = 0; k < 6; k++) {
            const float4* hu = h4 + (size_t)ibA[k] * 2 * NBB + lane;
            gA[2 * k] = hu[0 * NBB]; gA[2 * k + 1] = hu[1 * NBB];
        }
        // B own issued early
        float4 fnlB = featH[(size_t)vB * NBB + lane];
        float4 vvB  = v4[(size_t)vB * NBB + lane];
        const float4* hoB = h4 + (size_t)vB * 2 * NBB + lane;
        float4 oB0 = hoB[0 * NBB], oB1 = hoB[1 * NBB];
        // accumulate A (k = 0..5, same order as round 9)
        float mA[16], nb[16];
#pragma unroll
        for (int i = 0; i < 16; i++) mA[i] = 0.f;
#pragma unroll
        for (int k = 0; k < 6; k++) {
            unpack8(gA[2 * k], nb); unpack8(gA[2 * k + 1], nb + 8);
#pragma unroll
            for (int i = 0; i < 16; i++) mA[i] += nb[i];
        }
        // B gathers in flight during A GEMM
        float4 gB[12];
#pragma unroll
        for (int k = 0; k < 6; k++) {
            const float4* hu = h4 + (size_t)ibB[k] * 2 * NBB + lane;
            gB[2 * k] = hu[0 * NBB]; gB[2 * k + 1] = hu[1 * NBB];
        }
        gemm_store(vA, fnlA, vvA, oA0, oA1, mA, 6);
        float mB[16];
#pragma unroll
        for (int i = 0; i < 16; i++) mB[i] = 0.f;
#pragma unroll
        for (int k = 0; k < 6; k++) {
            unpack8(gB[2 * k], nb); unpack8(gB[2 * k + 1], nb + 8);
#pragma unroll
            for (int i = 0; i < 16; i++) mB[i] += nb[i];
        }
        gemm_store(vB, fnlB, vvB, oB0, oB1, mB, 6);
    } else {
#pragma unroll 1
        for (int s = 0; s < 2; s++) {
            int vi = (s == 0) ? vA : vB;
            const int* ib = (s == 0) ? ibA : ibB;
            int d = (s == 0) ? dA : dB;
            float4 fnl = featH[(size_t)vi * NBB + lane];
            float4 vv  = v4[(size_t)vi * NBB + lane];
            const float4* ho = h4 + (size_t)vi * 2 * NBB + lane;
            float4 o0 = ho[0 * NBB], o1 = ho[1 * NBB];
            float m[16], nb[16];
#pragma unroll
            for (int i = 0; i < 16; i++) m[i] = 0.f;
#pragma unroll
            for (int k = 0; k < 6; k++)
                if (k < d) {
                    const float4* hu = h4 + (size_t)ib[k] * 2 * NBB + lane;
                    unpack8(hu[0 * NBB], nb); unpack8(hu[1 * NBB], nb + 8);
#pragma unroll
                    for (int i = 0; i < 16; i++) m[i] += nb[i];
                }
            gemm_store(vi, fnl, vv, o0, o1, m, d);
        }
    }
}

// ---------------- output: (2,B,V,4) = (v*size, sulc), NEW->orig indirection ----------------
__global__ __launch_bounds__(256) void k_out(const float4* __restrict__ v4,
                                             const float* __restrict__ csz,
                                             const int* __restrict__ newid,
                                             float4* __restrict__ out) {
    int lane = threadIdx.x & 63;
    int vi = rfl(blockIdx.x * 4 + (threadIdx.x >> 6));   // ORIGINAL vertex id
    if (vi >= NV) return;
    int nid = rfl(newid[vi]);
    float4 o = v4[(size_t)nid * NBB + lane];
    float4 r;
    r.x = o.x * csz[(3 + 0) * NBB + lane];
    r.y = o.y * csz[(3 + 1) * NBB + lane];
    r.z = o.z * csz[(3 + 2) * NBB + lane];
    r.w = o.w;
    out[(size_t)lane * NV + vi] = r;   // lane = hemi*32 + b matches (2,B,V,4)
}

extern "C" void kernel_launch(void* const* d_in, const int* in_sizes, int n_in,
                              void* d_out, int out_size, void* d_ws, size_t ws_size,
                              hipStream_t stream) {
    const float* lh  = (const float*)d_in[0];
    const float* rh  = (const float*)d_in[1];
    const float* W1s = (const float*)d_in[2];
    const float* W1n = (const float*)d_in[3];
    const float* b1  = (const float*)d_in[4];
    const float* W2s = (const float*)d_in[5];
    const float* W2n = (const float*)d_in[6];
    const float* b2  = (const float*)d_in[7];
    const float* Wo  = (const float*)d_in[8];
    const float* bo  = (const float*)d_in[9];
    const int* faces = (const int*)d_in[10];

    float* ws    = (float*)d_ws;
    float4* v4   = (float4*)(ws + OFF_V);
    float4* ftH  = (float4*)(ws + OFF_FEAT);
    float4* h4   = (float4*)(ws + OFF_H);
    float* part  = ws + OFF_H;                // bbox partials borrow h's space pre-loop
    float* csz   = ws + OFF_CSZ;
    int* ibase   = (int*)(ws + OFF_INT);
    int* deg     = ibase;
    int* nbrB    = ibase + (size_t)NV;
    int* nbrC    = ibase + (size_t)7 * NV;
    int* newid   = ibase + (size_t)13 * NV;
    int* order   = ibase + (size_t)14 * NV;
    int* adjB8   = ibase + (size_t)16 * NV;   // 16*NV ints from 16B-aligned base -> aligned
    int* adjC8   = ibase + (size_t)24 * NV;

    build_perm_host();                        // once per process, pure combinatorics
    hipMemcpyAsync(newid, g_newid, NV * sizeof(int), hipMemcpyHostToDevice, stream);
    hipMemcpyAsync(order, g_order, NV * sizeof(int), hipMemcpyHostToDevice, stream);

    dim3 gv4((NV + 3) / 4);                   // 1 vertex/wave kernels (k_out)
    dim3 gv2((NPAIR + 3) / 4);                // 1 PAIR/wave loop kernels: 1281 blocks

    k_zero<<<(NV + 255) / 256, 256, 0, stream>>>(deg, NV);
    k_build<<<(NF + 255) / 256, 256, 0, stream>>>(faces, deg, nbrB, nbrC);
    k_remap<<<(NV + 255) / 256, 256, 0, stream>>>(deg, nbrB, nbrC, newid, order, adjB8, adjC8);
    k_bbox1<<<dim3(NCHUNK, NBB), 256, 0, stream>>>(lh, rh, part);
    k_bbox2<<<1, 64, 0, stream>>>(part, csz);
    k_normT<<<dim3(NCHUNK, NBB), 256, 0, stream>>>(lh, rh, csz, newid, v4);

    for (int s = 0; s < NSTEPS; s++) {
        k_geom<<<gv2, 256, 0, stream>>>(v4, adjB8, adjC8, ftH);
        k_layer1<<<gv2, 256, 0, stream>>>(v4, ftH, adjB8, W1s, W1n, b1, h4);
        k_layer2<<<gv2, 256, 0, stream>>>(h4, ftH, adjB8, W2s, W2n, b2, Wo, bo, v4);
    }
    k_out<<<gv4, 256, 0, stream>>>(v4, csz, newid, (float4*)d_out);
}

// Round 11
// 775.170 us; speedup vs baseline: 6.1282x; 6.1282x over previous
//
#include <hip/hip_runtime.h>
#include <hip/hip_fp16.h>
#include <vector>
#include <array>
#include <map>
#include <algorithm>

#define BATCH 32
#define NV    10242
#define NF    20480
#define NBB   64          // 2 hemis * 32 batches ; lane = bb
#define NSTEPS 10
#define STEPSZ 0.1f
#define EPSV   1e-8f
#define NCHUNK 16
#define CHSZ   641        // ceil(NV/NCHUNK)

// ---------------- workspace layout: lane = bb ----------------
// v     : [NV][NBB] float4   (x, y, z, sulc)       -- NEW (BFS) id, f32
// featH : [NV][NBB] float4 = 8 x fp16 {nx,ny,nz, lx,ly,lz, 0,0}
// h     : [NV][2][NBB] float4 = 16 x fp16 channels
// NOTE: fp16 is STORAGE ONLY. All accumulation is f32 (round-8 lesson:
// packed __hadd2 accumulation pushed absmax 2.25 -> 4.75, over the gate).
// NOTE2 (round-10 lesson): do NOT pipeline two vertices per wave — the
// compiler hoists the second vertex's gathers and both register sets go
// live simultaneously -> VGPR 256 + 663 MB scratch spill. One vertex/wave.
static constexpr size_t OFF_V    = 0;                                  // floats
static constexpr size_t OFF_FEAT = OFF_V    + (size_t)NV * NBB * 4;
static constexpr size_t OFF_H    = OFF_FEAT + (size_t)NV * NBB * 4;
static constexpr size_t OFF_CSZ  = OFF_H    + (size_t)NV * NBB * 8;    // [6][NBB] ctr(3),size(3)
static constexpr size_t OFF_INT  = OFF_CSZ  + 6 * NBB;
// int region: deg @0  nbrB @NV..7NV  nbrC @7NV..13NV  newid @13NV  order @14NV [pad]
//   adjB8 @16NV..24NV : {b0..b5, deg, 0}   adjC8 @24NV..32NV : {c0..c5, 0, 0}

__device__ __forceinline__ int rfl(int x) { return __builtin_amdgcn_readfirstlane(x); }

union HF4 { float4 f4; __half2 h2[4]; };

__device__ __forceinline__ float4 pack8(const float* x) {
    HF4 u;
    u.h2[0] = __floats2half2_rn(x[0], x[1]);
    u.h2[1] = __floats2half2_rn(x[2], x[3]);
    u.h2[2] = __floats2half2_rn(x[4], x[5]);
    u.h2[3] = __floats2half2_rn(x[6], x[7]);
    return u.f4;
}
__device__ __forceinline__ void unpack8(float4 v, float* x) {
    HF4 u;
    u.f4 = v;
#pragma unroll
    for (int i = 0; i < 4; i++) {
        float2 f = __half22float2(u.h2[i]);
        x[2 * i] = f.x; x[2 * i + 1] = f.y;
    }
}

// bijective XCD chunking swizzle: contiguous NEW-id vertex range per XCD
__device__ __forceinline__ int swz(int b, int n) {
    int q = n >> 3, r = n & 7;
    int x = b & 7, i = b >> 3;
    return (x < r ? x * (q + 1) : r * (q + 1) + (x - r) * q) + i;
}

// ================= host-side BFS permutation (once per process) =================
static int g_order[NV], g_newid[NV];
static bool g_perm_built = false;

static void build_perm_host() {
    if (g_perm_built) return;
    int nv = 12;
    std::vector<std::array<int, 3>> f = {
        {0,11,5},{0,5,1},{0,1,7},{0,7,10},{0,10,11},
        {1,5,9},{5,11,4},{11,10,2},{10,7,6},{7,1,8},
        {3,9,4},{3,4,2},{3,2,6},{3,6,8},{3,8,9},
        {4,9,5},{2,4,11},{6,2,10},{8,6,7},{9,8,1}};
    for (int s = 0; s < 5; s++) {
        std::map<long long, int> cache;
        auto mid = [&](int a, int b) {
            long long key = (long long)std::min(a, b) * 1000000LL + std::max(a, b);
            auto it = cache.find(key);
            if (it != cache.end()) return it->second;
            int idx = nv++;
            cache.emplace(key, idx);
            return idx;
        };
        std::vector<std::array<int, 3>> nf;
        nf.reserve(f.size() * 4);
        for (auto& fc : f) {
            int a = fc[0], b = fc[1], c = fc[2];
            int ab = mid(a, b), bc = mid(b, c), ca = mid(c, a);
            nf.push_back({a, ab, ca}); nf.push_back({b, bc, ab});
            nf.push_back({c, ca, bc}); nf.push_back({ab, bc, ca});
        }
        f.swap(nf);
    }
    std::vector<std::array<int, 6>> nbr(NV);
    std::vector<int> deg(NV, 0);
    for (auto& fc : f)
        for (int c = 0; c < 3; c++) {
            int vtx = fc[c];
            if (vtx < NV && deg[vtx] < 6) nbr[vtx][deg[vtx]++] = fc[(c + 1) % 3];
        }
    std::vector<int> vis(NV, -1);
    int tail = 0;
    g_order[tail] = 0; vis[0] = tail; tail++;
    for (int head = 0; head < tail; head++) {
        int u = g_order[head];
        for (int k = 0; k < deg[u]; k++) {
            int w = nbr[u][k];
            if (vis[w] < 0) { vis[w] = tail; g_order[tail++] = w; }
        }
    }
    for (int i = 0; i < NV; i++)
        if (vis[i] < 0) { vis[i] = tail; g_order[tail++] = i; }
    for (int i = 0; i < NV; i++) g_newid[i] = vis[i];
    g_perm_built = true;
}

// ---------------- adjacency build (once per launch) ----------------
__global__ __launch_bounds__(256) void k_zero(int* p, int n) {
    int i = blockIdx.x * 256 + threadIdx.x;
    if (i < n) p[i] = 0;
}

__global__ __launch_bounds__(256) void k_build(const int* __restrict__ faces,
                                               int* deg, int* nbrB, int* nbrC) {
    int fi = blockIdx.x * 256 + threadIdx.x;
    if (fi >= NF) return;
    int vv[3] = {faces[fi * 3 + 0], faces[fi * 3 + 1], faces[fi * 3 + 2]};
#pragma unroll
    for (int c = 0; c < 3; c++) {
        int vtx = vv[c];
        int s = atomicAdd(&deg[vtx], 1);
        nbrB[vtx * 6 + s] = vv[(c + 1) % 3];   // next corner = dedup'd neighbor
        nbrC[vtx * 6 + s] = vv[(c + 2) % 3];   // prev corner
    }
}

// ---------------- remap adjacency to new ids, packed 8-int rows ----------------
__global__ __launch_bounds__(256) void k_remap(const int* __restrict__ deg,
                                               const int* __restrict__ nbrB,
                                               const int* __restrict__ nbrC,
                                               const int* __restrict__ newid,
                                               const int* __restrict__ order,
                                               int* __restrict__ adjB8,
                                               int* __restrict__ adjC8) {
    int n = blockIdx.x * 256 + threadIdx.x;
    if (n >= NV) return;
    int o = order[n];
    int d = deg[o];
    int b[8], c[8];
#pragma unroll
    for (int k = 0; k < 6; k++) {
        b[k] = (k < d) ? newid[nbrB[o * 6 + k]] : 0;
        c[k] = (k < d) ? newid[nbrC[o * 6 + k]] : 0;
    }
    b[6] = d; b[7] = 0; c[6] = 0; c[7] = 0;
#pragma unroll
    for (int k = 0; k < 8; k++) { adjB8[n * 8 + k] = b[k]; adjC8[n * 8 + k] = c[k]; }
}

// ---------------- bbox phase 1: per-(chunk,bb) partial min/max ----------------
__global__ __launch_bounds__(256) void k_bbox1(const float* __restrict__ lh,
                                               const float* __restrict__ rh,
                                               float* __restrict__ part) {
    int ch = blockIdx.x, bb = blockIdx.y;
    const float* src = (bb < BATCH) ? (lh + (size_t)bb * NV * 3)
                                    : (rh + (size_t)(bb - BATCH) * NV * 3);
    int lo = ch * CHSZ, hi = min(lo + CHSZ, NV);
    __shared__ float smin[3][256], smax[3][256];
    float mn[3] = {1e30f, 1e30f, 1e30f}, mx[3] = {-1e30f, -1e30f, -1e30f};
    for (int i = lo + threadIdx.x; i < hi; i += 256) {
#pragma unroll
        for (int c = 0; c < 3; c++) {
            float x = src[i * 3 + c];
            mn[c] = fminf(mn[c], x);
            mx[c] = fmaxf(mx[c], x);
        }
    }
#pragma unroll
    for (int c = 0; c < 3; c++) { smin[c][threadIdx.x] = mn[c]; smax[c][threadIdx.x] = mx[c]; }
    __syncthreads();
    for (int s = 128; s > 0; s >>= 1) {
        if (threadIdx.x < s) {
#pragma unroll
            for (int c = 0; c < 3; c++) {
                smin[c][threadIdx.x] = fminf(smin[c][threadIdx.x], smin[c][threadIdx.x + s]);
                smax[c][threadIdx.x] = fmaxf(smax[c][threadIdx.x], smax[c][threadIdx.x + s]);
            }
        }
        __syncthreads();
    }
    if (threadIdx.x == 0) {
        float* p = part + ((size_t)ch * NBB + bb) * 6;
#pragma unroll
        for (int c = 0; c < 3; c++) { p[c] = smin[c][0]; p[3 + c] = smax[c][0]; }
    }
}

// ---------------- bbox phase 2: combine -> csz ----------------
__global__ __launch_bounds__(64) void k_bbox2(const float* __restrict__ part,
                                              float* __restrict__ csz) {
    int bb = threadIdx.x;
    float mn[3] = {1e30f, 1e30f, 1e30f}, mx[3] = {-1e30f, -1e30f, -1e30f};
    for (int ch = 0; ch < NCHUNK; ch++) {
        const float* p = part + ((size_t)ch * NBB + bb) * 6;
#pragma unroll
        for (int c = 0; c < 3; c++) {
            mn[c] = fminf(mn[c], p[c]);
            mx[c] = fmaxf(mx[c], p[3 + c]);
        }
    }
#pragma unroll
    for (int c = 0; c < 3; c++) {
        float ctr = 0.5f * (mn[c] + mx[c]);
        csz[c * NBB + bb] = ctr;
        csz[(3 + c) * NBB + bb] = mx[c] - ctr;
    }
}

// ---------------- normalize + transpose-in, scattered to NEW ids ----------------
__global__ __launch_bounds__(256) void k_normT(const float* __restrict__ lh,
                                               const float* __restrict__ rh,
                                               const float* __restrict__ csz,
                                               const int* __restrict__ newid,
                                               float4* __restrict__ v4) {
    int ch = blockIdx.x, bb = blockIdx.y;
    const float* src = (bb < BATCH) ? (lh + (size_t)bb * NV * 3)
                                    : (rh + (size_t)(bb - BATCH) * NV * 3);
    float ctr[3], isz[3];
#pragma unroll
    for (int c = 0; c < 3; c++) {
        ctr[c] = csz[c * NBB + bb];
        isz[c] = 1.f / csz[(3 + c) * NBB + bb];
    }
    int lo = ch * CHSZ, hi = min(lo + CHSZ, NV);
    for (int i = lo + threadIdx.x; i < hi; i += 256) {
        float4 o;
        o.x = (src[i * 3 + 0] - ctr[0]) * isz[0];
        o.y = (src[i * 3 + 1] - ctr[1]) * isz[1];
        o.z = (src[i * 3 + 2] - ctr[2]) * isz[2];
        o.w = 0.f;                               // sulc lives in v.w
        v4[(size_t)newid[i] * NBB + bb] = o;
    }
}

// ---------------- per-step: geometry -> featH = fp16x8 {n, 0.5*lap} ----------------
__global__ __launch_bounds__(256) void k_geom(const float4* __restrict__ v4,
                                              const int* __restrict__ adjB8,
                                              const int* __restrict__ adjC8,
                                              float4* __restrict__ featH) {
    int lane = threadIdx.x & 63;
    int blk = swz(blockIdx.x, gridDim.x);
    int vi = rfl(blk * 4 + (threadIdx.x >> 6));
    if (vi >= NV) return;
    float sgn = (lane < BATCH) ? 1.f : -1.f;   // rh: reversed winding flips face normals
    int4 blo = *(const int4*)&adjB8[(size_t)vi * 8];
    int4 bhi = *(const int4*)&adjB8[(size_t)vi * 8 + 4];
    int4 clo = *(const int4*)&adjC8[(size_t)vi * 8];
    int4 chi = *(const int4*)&adjC8[(size_t)vi * 8 + 4];
    int d = rfl(bhi.z);
    int ib[6] = {rfl(blo.x), rfl(blo.y), rfl(blo.z), rfl(blo.w), rfl(bhi.x), rfl(bhi.y)};
    int ic[6] = {rfl(clo.x), rfl(clo.y), rfl(clo.z), rfl(clo.w), rfl(chi.x), rfl(chi.y)};
    float4 a = v4[(size_t)vi * NBB + lane];
    float vnx = 0.f, vny = 0.f, vnz = 0.f, lx = 0.f, ly = 0.f, lz = 0.f;

    auto acc = [&](float4 b, float4 c) {
        float e1x = b.x - a.x, e1y = b.y - a.y, e1z = b.z - a.z;   // B - A
        float e2x = c.x - a.x, e2y = c.y - a.y, e2z = c.z - a.z;   // C - A
        float fnx = e1y * e2z - e1z * e2y;                         // face normal
        float fny = e1z * e2x - e1x * e2z;
        float fnz = e1x * e2y - e1y * e2x;
        vnx += fnx; vny += fny; vnz += fnz;
        float rd = 1.f / (sqrtf(fnx * fnx + fny * fny + fnz * fnz) + EPSV);
        float ux = c.x - b.x, uy = c.y - b.y, uz = c.z - b.z;
        float wx = a.x - b.x, wy = a.y - b.y, wz = a.z - b.z;
        float cB = (ux * wx + uy * wy + uz * wz) * rd;             // cot at B
        float rx = a.x - c.x, ry = a.y - c.y, rz = a.z - c.z;
        float sx = b.x - c.x, sy = b.y - c.y, sz2 = b.z - c.z;
        float cC = (rx * sx + ry * sy + rz * sz2) * rd;            // cot at C
        lx += cC * e1x + cB * e2x;
        ly += cC * e1y + cB * e2y;
        lz += cC * e1z + cB * e2z;
    };

    if (d == 6) {
#pragma unroll
        for (int g = 0; g < 2; g++) {
            float4 pb[3], pc[3];
#pragma unroll
            for (int k = 0; k < 3; k++) {
                pb[k] = v4[(size_t)ib[g * 3 + k] * NBB + lane];
                pc[k] = v4[(size_t)ic[g * 3 + k] * NBB + lane];
            }
#pragma unroll
            for (int k = 0; k < 3; k++) acc(pb[k], pc[k]);
        }
    } else {
#pragma unroll
        for (int k = 0; k < 6; k++)
            if (k < d) acc(v4[(size_t)ib[k] * NBB + lane], v4[(size_t)ic[k] * NBB + lane]);
    }
    vnx *= sgn; vny *= sgn; vnz *= sgn;
    float nn = 1.f / (sqrtf(vnx * vnx + vny * vny + vnz * vnz) + EPSV);
    float nl[8] = {vnx * nn, vny * nn, vnz * nn, 0.5f * lx, 0.5f * ly, 0.5f * lz, 0.f, 0.f};
    featH[(size_t)vi * NBB + lane] = pack8(nl);
}

// ---------------- per-step: layer1  h = relu(feat@W1s + mean_nbr(feat)@W1n + b1) ----------------
// f32 accumulation; gathers in 2x3 rounds; hv packed incrementally
__global__ __launch_bounds__(256) void k_layer1(const float4* __restrict__ v4,
                                                const float4* __restrict__ featH,
                                                const int* __restrict__ adjB8,
                                                const float* __restrict__ W1s,
                                                const float* __restrict__ W1n,
                                                const float* __restrict__ b1,
                                                float4* __restrict__ h4) {
    __shared__ float sWs[144], sWn[144], sb[16];
    int t = threadIdx.x;
    if (t < 144) { sWs[t] = W1s[t]; sWn[t] = W1n[t]; }
    if (t < 16) sb[t] = b1[t];
    __syncthreads();
    int lane = t & 63;
    int blk = swz(blockIdx.x, gridDim.x);
    int vi = rfl(blk * 4 + (t >> 6));
    if (vi >= NV) return;
    int4 blo = *(const int4*)&adjB8[(size_t)vi * 8];
    int4 bhi = *(const int4*)&adjB8[(size_t)vi * 8 + 4];
    int d = rfl(bhi.z);
    int ib[6] = {rfl(blo.x), rfl(blo.y), rfl(blo.z), rfl(blo.w), rfl(bhi.x), rfl(bhi.y)};
    float4 ov  = v4[(size_t)vi * NBB + lane];
    float4 onl = featH[(size_t)vi * NBB + lane];
    float m[9] = {0.f, 0.f, 0.f, 0.f, 0.f, 0.f, 0.f, 0.f, 0.f};
    float nl[8];
    if (d == 6) {
#pragma unroll
        for (int g = 0; g < 2; g++) {
            float4 gv[3], gn[3];
#pragma unroll
            for (int k = 0; k < 3; k++) {
                gv[k] = v4[(size_t)ib[g * 3 + k] * NBB + lane];
                gn[k] = featH[(size_t)ib[g * 3 + k] * NBB + lane];
            }
#pragma unroll
            for (int k = 0; k < 3; k++) {
                m[0] += gv[k].x; m[1] += gv[k].y; m[2] += gv[k].z;
                unpack8(gn[k], nl);
                m[3] += nl[0]; m[4] += nl[1]; m[5] += nl[2];
                m[6] += nl[3]; m[7] += nl[4]; m[8] += nl[5];
            }
        }
    } else {
#pragma unroll
        for (int k = 0; k < 6; k++)
            if (k < d) {
                float4 gv = v4[(size_t)ib[k] * NBB + lane];
                float4 gn = featH[(size_t)ib[k] * NBB + lane];
                m[0] += gv.x; m[1] += gv.y; m[2] += gv.z;
                unpack8(gn, nl);
                m[3] += nl[0]; m[4] += nl[1]; m[5] += nl[2];
                m[6] += nl[3]; m[7] += nl[4]; m[8] += nl[5];
            }
    }
    unpack8(onl, nl);
    float own[9] = {ov.x, ov.y, ov.z, nl[0], nl[1], nl[2], nl[3], nl[4], nl[5]};
    float inv = 1.f / (float)d;
#pragma unroll
    for (int i = 0; i < 9; i++) m[i] *= inv;
    HF4 h0, h1;
#pragma unroll
    for (int jp = 0; jp < 8; jp++) {         // channel pairs -> pack directly
        float a0 = sb[2 * jp], a1 = sb[2 * jp + 1];
#pragma unroll
        for (int i = 0; i < 9; i++) {
            a0 += own[i] * sWs[i * 16 + 2 * jp]     + m[i] * sWn[i * 16 + 2 * jp];
            a1 += own[i] * sWs[i * 16 + 2 * jp + 1] + m[i] * sWn[i * 16 + 2 * jp + 1];
        }
        __half2 p = __floats2half2_rn(fmaxf(a0, 0.f), fmaxf(a1, 0.f));
        if (jp < 4) h0.h2[jp] = p; else h1.h2[jp - 4] = p;
    }
    float4* hp = h4 + (size_t)vi * 2 * NBB + lane;
    hp[0 * NBB] = h0.f4;
    hp[1 * NBB] = h1.f4;
}

// ---------------- per-step: layer2 + output head + state update (sulc in v.w) ----------------
// f32 accumulation, 2x3-neighbor gather rounds, output head folded into GEMM loop
__global__ __launch_bounds__(256) void k_layer2(const float4* __restrict__ h4,
                                                const float4* __restrict__ featH,
                                                const int* __restrict__ adjB8,
                                                const float* __restrict__ W2s,
                                                const float* __restrict__ W2n,
                                                const float* __restrict__ b2,
                                                const float* __restrict__ Wo,
                                                const float* __restrict__ bo,
                                                float4* __restrict__ v4) {
    __shared__ float sWs[256], sWn[256], sb[16], sWo[48], sbo[3];
    int t = threadIdx.x;
    sWs[t] = W2s[t];
    sWn[t] = W2n[t];
    if (t < 16) sb[t] = b2[t];
    if (t < 48) sWo[t] = Wo[t];
    if (t < 3) sbo[t] = bo[t];
    __syncthreads();
    int lane = t & 63;
    int blk = swz(blockIdx.x, gridDim.x);
    int vi = rfl(blk * 4 + (t >> 6));
    if (vi >= NV) return;
    int4 blo = *(const int4*)&adjB8[(size_t)vi * 8];
    int4 bhi = *(const int4*)&adjB8[(size_t)vi * 8 + 4];
    int d = rfl(bhi.z);
    int ib[6] = {rfl(blo.x), rfl(blo.y), rfl(blo.z), rfl(blo.w), rfl(bhi.x), rfl(bhi.y)};
    // epilogue operands issued early (consumed last)
    float4 fnl = featH[(size_t)vi * NBB + lane];   // this step's normal
    float4 vv = v4[(size_t)vi * NBB + lane];
    const float4* ho = h4 + (size_t)vi * 2 * NBB + lane;
    float4 oA = ho[0 * NBB], oB = ho[1 * NBB];
    float m[16], nb[16];
#pragma unroll
    for (int i = 0; i < 16; i++) m[i] = 0.f;
    if (d == 6) {
#pragma unroll
        for (int g = 0; g < 2; g++) {
            float4 gA[3], gB[3];
#pragma unroll
            for (int k = 0; k < 3; k++) {    // 3 neighbors (6 float4) in flight
                const float4* hu = h4 + (size_t)ib[g * 3 + k] * 2 * NBB + lane;
                gA[k] = hu[0 * NBB]; gB[k] = hu[1 * NBB];
            }
#pragma unroll
            for (int k = 0; k < 3; k++) {
                unpack8(gA[k], nb); unpack8(gB[k], nb + 8);
#pragma unroll
                for (int i = 0; i < 16; i++) m[i] += nb[i];
            }
        }
    } else {
#pragma unroll
        for (int k = 0; k < 6; k++)
            if (k < d) {
                const float4* hu = h4 + (size_t)ib[k] * 2 * NBB + lane;
                unpack8(hu[0 * NBB], nb); unpack8(hu[1 * NBB], nb + 8);
#pragma unroll
                for (int i = 0; i < 16; i++) m[i] += nb[i];
            }
    }
    float own[16];
    unpack8(oA, own); unpack8(oB, own + 8);
    float inv = 1.f / (float)d;
#pragma unroll
    for (int i = 0; i < 16; i++) m[i] *= inv;
    float dv[3] = {sbo[0], sbo[1], sbo[2]};
#pragma unroll
    for (int j = 0; j < 16; j++) {           // output head folded in: no h2[16]
        float acc = sb[j];
#pragma unroll
        for (int i = 0; i < 16; i++) acc += own[i] * sWs[i * 16 + j] + m[i] * sWn[i * 16 + j];
        acc = fmaxf(acc, 0.f);
        dv[0] += acc * sWo[j * 3 + 0];
        dv[1] += acc * sWo[j * 3 + 1];
        dv[2] += acc * sWo[j * 3 + 2];
    }
    float nlo[8];
    unpack8(fnl, nlo);                       // nlo[0..2] = this step's normal
    vv.x += STEPSZ * dv[0];
    vv.y += STEPSZ * dv[1];
    vv.z += STEPSZ * dv[2];
    vv.w += STEPSZ * (nlo[0] * dv[0] + nlo[1] * dv[1] + nlo[2] * dv[2]);
    v4[(size_t)vi * NBB + lane] = vv;
}

// ---------------- output: (2,B,V,4) = (v*size, sulc), NEW->orig indirection ----------------
__global__ __launch_bounds__(256) void k_out(const float4* __restrict__ v4,
                                             const float* __restrict__ csz,
                                             const int* __restrict__ newid,
                                             float4* __restrict__ out) {
    int lane = threadIdx.x & 63;
    int vi = rfl(blockIdx.x * 4 + (threadIdx.x >> 6));   // ORIGINAL vertex id
    if (vi >= NV) return;
    int nid = rfl(newid[vi]);
    float4 o = v4[(size_t)nid * NBB + lane];
    float4 r;
    r.x = o.x * csz[(3 + 0) * NBB + lane];
    r.y = o.y * csz[(3 + 1) * NBB + lane];
    r.z = o.z * csz[(3 + 2) * NBB + lane];
    r.w = o.w;
    out[(size_t)lane * NV + vi] = r;   // lane = hemi*32 + b matches (2,B,V,4)
}

extern "C" void kernel_launch(void* const* d_in, const int* in_sizes, int n_in,
                              void* d_out, int out_size, void* d_ws, size_t ws_size,
                              hipStream_t stream) {
    const float* lh  = (const float*)d_in[0];
    const float* rh  = (const float*)d_in[1];
    const float* W1s = (const float*)d_in[2];
    const float* W1n = (const float*)d_in[3];
    const float* b1  = (const float*)d_in[4];
    const float* W2s = (const float*)d_in[5];
    const float* W2n = (const float*)d_in[6];
    const float* b2  = (const float*)d_in[7];
    const float* Wo  = (const float*)d_in[8];
    const float* bo  = (const float*)d_in[9];
    const int* faces = (const int*)d_in[10];

    float* ws    = (float*)d_ws;
    float4* v4   = (float4*)(ws + OFF_V);
    float4* ftH  = (float4*)(ws + OFF_FEAT);
    float4* h4   = (float4*)(ws + OFF_H);
    float* part  = ws + OFF_H;                // bbox partials borrow h's space pre-loop
    float* csz   = ws + OFF_CSZ;
    int* ibase   = (int*)(ws + OFF_INT);
    int* deg     = ibase;
    int* nbrB    = ibase + (size_t)NV;
    int* nbrC    = ibase + (size_t)7 * NV;
    int* newid   = ibase + (size_t)13 * NV;
    int* order   = ibase + (size_t)14 * NV;
    int* adjB8   = ibase + (size_t)16 * NV;   // 16*NV ints from 16B-aligned base -> aligned
    int* adjC8   = ibase + (size_t)24 * NV;

    build_perm_host();                        // once per process, pure combinatorics
    hipMemcpyAsync(newid, g_newid, NV * sizeof(int), hipMemcpyHostToDevice, stream);
    hipMemcpyAsync(order, g_order, NV * sizeof(int), hipMemcpyHostToDevice, stream);

    const int WPB = 4;                        // waves (vertices) per block
    dim3 gv((NV + WPB - 1) / WPB);            // 2561 blocks, wave-per-vertex

    k_zero<<<(NV + 255) / 256, 256, 0, stream>>>(deg, NV);
    k_build<<<(NF + 255) / 256, 256, 0, stream>>>(faces, deg, nbrB, nbrC);
    k_remap<<<(NV + 255) / 256, 256, 0, stream>>>(deg, nbrB, nbrC, newid, order, adjB8, adjC8);
    k_bbox1<<<dim3(NCHUNK, NBB), 256, 0, stream>>>(lh, rh, part);
    k_bbox2<<<1, 64, 0, stream>>>(part, csz);
    k_normT<<<dim3(NCHUNK, NBB), 256, 0, stream>>>(lh, rh, csz, newid, v4);

    for (int s = 0; s < NSTEPS; s++) {
        k_geom<<<gv, 256, 0, stream>>>(v4, adjB8, adjC8, ftH);
        k_layer1<<<gv, 256, 0, stream>>>(v4, ftH, adjB8, W1s, W1n, b1, h4);
        k_layer2<<<gv, 256, 0, stream>>>(h4, ftH, adjB8, W2s, W2n, b2, Wo, bo, v4);
    }
    k_out<<<gv, 256, 0, stream>>>(v4, csz, newid, (float4*)d_out);
}

// Round 12
// 769.602 us; speedup vs baseline: 6.1725x; 1.0072x over previous
//
#include <hip/hip_runtime.h>
#include <hip/hip_fp16.h>
#include <vector>
#include <array>
#include <map>
#include <algorithm>

#define BATCH 32
#define NV    10242
#define NF    20480
#define NBB   64          // 2 hemis * 32 batches ; lane = bb
#define NSTEPS 10
#define STEPSZ 0.1f
#define EPSV   1e-8f
#define NCHUNK 16
#define CHSZ   641        // ceil(NV/NCHUNK)

// ---------------- workspace layout: lane = bb ----------------
// v     : [NV][NBB] float4   (x, y, z, sulc)       -- NEW (BFS) id, f32
// featH : [NV][NBB] float4 = 8 x fp16 {nx,ny,nz, lx,ly,lz, 0,0}
// h     : [NV][2][NBB] float4 = 16 x fp16 channels
// NOTE: fp16 is STORAGE ONLY. All accumulation is f32 (round-8 lesson:
// packed __hadd2 accumulation pushed absmax 2.25 -> 4.75, over the gate).
// NOTE2 (round-10 lesson): do NOT pipeline two vertices per wave — the
// compiler hoists the second vertex's gathers and both register sets go
// live simultaneously -> VGPR 256 + 663 MB scratch spill. One vertex/wave.
static constexpr size_t OFF_V    = 0;                                  // floats
static constexpr size_t OFF_FEAT = OFF_V    + (size_t)NV * NBB * 4;
static constexpr size_t OFF_H    = OFF_FEAT + (size_t)NV * NBB * 4;
static constexpr size_t OFF_CSZ  = OFF_H    + (size_t)NV * NBB * 8;    // [6][NBB] ctr(3),size(3)
static constexpr size_t OFF_INT  = OFF_CSZ  + 6 * NBB;
// int region: deg @0  nbrB @NV..7NV  nbrC @7NV..13NV  newid @13NV  order @14NV [pad]
//   adjB8 @16NV..24NV : {b0..b5, deg, 0}   adjC8 @24NV..32NV : {c0..c5, 0, 0}

__device__ __forceinline__ int rfl(int x) { return __builtin_amdgcn_readfirstlane(x); }

union HF4 { float4 f4; __half2 h2[4]; };

__device__ __forceinline__ float4 pack8(const float* x) {
    HF4 u;
    u.h2[0] = __floats2half2_rn(x[0], x[1]);
    u.h2[1] = __floats2half2_rn(x[2], x[3]);
    u.h2[2] = __floats2half2_rn(x[4], x[5]);
    u.h2[3] = __floats2half2_rn(x[6], x[7]);
    return u.f4;
}
__device__ __forceinline__ void unpack8(float4 v, float* x) {
    HF4 u;
    u.f4 = v;
#pragma unroll
    for (int i = 0; i < 4; i++) {
        float2 f = __half22float2(u.h2[i]);
        x[2 * i] = f.x; x[2 * i + 1] = f.y;
    }
}

// bijective XCD chunking swizzle: contiguous NEW-id vertex range per XCD
__device__ __forceinline__ int swz(int b, int n) {
    int q = n >> 3, r = n & 7;
    int x = b & 7, i = b >> 3;
    return (x < r ? x * (q + 1) : r * (q + 1) + (x - r) * q) + i;
}

// ================= host-side BFS permutation (once per process) =================
static int g_order[NV], g_newid[NV];
static bool g_perm_built = false;

static void build_perm_host() {
    if (g_perm_built) return;
    int nv = 12;
    std::vector<std::array<int, 3>> f = {
        {0,11,5},{0,5,1},{0,1,7},{0,7,10},{0,10,11},
        {1,5,9},{5,11,4},{11,10,2},{10,7,6},{7,1,8},
        {3,9,4},{3,4,2},{3,2,6},{3,6,8},{3,8,9},
        {4,9,5},{2,4,11},{6,2,10},{8,6,7},{9,8,1}};
    for (int s = 0; s < 5; s++) {
        std::map<long long, int> cache;
        auto mid = [&](int a, int b) {
            long long key = (long long)std::min(a, b) * 1000000LL + std::max(a, b);
            auto it = cache.find(key);
            if (it != cache.end()) return it->second;
            int idx = nv++;
            cache.emplace(key, idx);
            return idx;
        };
        std::vector<std::array<int, 3>> nf;
        nf.reserve(f.size() * 4);
        for (auto& fc : f) {
            int a = fc[0], b = fc[1], c = fc[2];
            int ab = mid(a, b), bc = mid(b, c), ca = mid(c, a);
            nf.push_back({a, ab, ca}); nf.push_back({b, bc, ab});
            nf.push_back({c, ca, bc}); nf.push_back({ab, bc, ca});
        }
        f.swap(nf);
    }
    std::vector<std::array<int, 6>> nbr(NV);
    std::vector<int> deg(NV, 0);
    for (auto& fc : f)
        for (int c = 0; c < 3; c++) {
            int vtx = fc[c];
            if (vtx < NV && deg[vtx] < 6) nbr[vtx][deg[vtx]++] = fc[(c + 1) % 3];
        }
    std::vector<int> vis(NV, -1);
    int tail = 0;
    g_order[tail] = 0; vis[0] = tail; tail++;
    for (int head = 0; head < tail; head++) {
        int u = g_order[head];
        for (int k = 0; k < deg[u]; k++) {
            int w = nbr[u][k];
            if (vis[w] < 0) { vis[w] = tail; g_order[tail++] = w; }
        }
    }
    for (int i = 0; i < NV; i++)
        if (vis[i] < 0) { vis[i] = tail; g_order[tail++] = i; }
    for (int i = 0; i < NV; i++) g_newid[i] = vis[i];
    g_perm_built = true;
}

// ---------------- adjacency build (once per launch) ----------------
__global__ __launch_bounds__(256) void k_zero(int* p, int n) {
    int i = blockIdx.x * 256 + threadIdx.x;
    if (i < n) p[i] = 0;
}

__global__ __launch_bounds__(256) void k_build(const int* __restrict__ faces,
                                               int* deg, int* nbrB, int* nbrC) {
    int fi = blockIdx.x * 256 + threadIdx.x;
    if (fi >= NF) return;
    int vv[3] = {faces[fi * 3 + 0], faces[fi * 3 + 1], faces[fi * 3 + 2]};
#pragma unroll
    for (int c = 0; c < 3; c++) {
        int vtx = vv[c];
        int s = atomicAdd(&deg[vtx], 1);
        nbrB[vtx * 6 + s] = vv[(c + 1) % 3];   // next corner = dedup'd neighbor
        nbrC[vtx * 6 + s] = vv[(c + 2) % 3];   // prev corner
    }
}

// ---------------- remap adjacency to new ids, packed 8-int rows ----------------
__global__ __launch_bounds__(256) void k_remap(const int* __restrict__ deg,
                                               const int* __restrict__ nbrB,
                                               const int* __restrict__ nbrC,
                                               const int* __restrict__ newid,
                                               const int* __restrict__ order,
                                               int* __restrict__ adjB8,
                                               int* __restrict__ adjC8) {
    int n = blockIdx.x * 256 + threadIdx.x;
    if (n >= NV) return;
    int o = order[n];
    int d = deg[o];
    int b[8], c[8];
#pragma unroll
    for (int k = 0; k < 6; k++) {
        b[k] = (k < d) ? newid[nbrB[o * 6 + k]] : 0;
        c[k] = (k < d) ? newid[nbrC[o * 6 + k]] : 0;
    }
    b[6] = d; b[7] = 0; c[6] = 0; c[7] = 0;
#pragma unroll
    for (int k = 0; k < 8; k++) { adjB8[n * 8 + k] = b[k]; adjC8[n * 8 + k] = c[k]; }
}

// ---------------- bbox phase 1: per-(chunk,bb) partial min/max ----------------
__global__ __launch_bounds__(256) void k_bbox1(const float* __restrict__ lh,
                                               const float* __restrict__ rh,
                                               float* __restrict__ part) {
    int ch = blockIdx.x, bb = blockIdx.y;
    const float* src = (bb < BATCH) ? (lh + (size_t)bb * NV * 3)
                                    : (rh + (size_t)(bb - BATCH) * NV * 3);
    int lo = ch * CHSZ, hi = min(lo + CHSZ, NV);
    __shared__ float smin[3][256], smax[3][256];
    float mn[3] = {1e30f, 1e30f, 1e30f}, mx[3] = {-1e30f, -1e30f, -1e30f};
    for (int i = lo + threadIdx.x; i < hi; i += 256) {
#pragma unroll
        for (int c = 0; c < 3; c++) {
            float x = src[i * 3 + c];
            mn[c] = fminf(mn[c], x);
            mx[c] = fmaxf(mx[c], x);
        }
    }
#pragma unroll
    for (int c = 0; c < 3; c++) { smin[c][threadIdx.x] = mn[c]; smax[c][threadIdx.x] = mx[c]; }
    __syncthreads();
    for (int s = 128; s > 0; s >>= 1) {
        if (threadIdx.x < s) {
#pragma unroll
            for (int c = 0; c < 3; c++) {
                smin[c][threadIdx.x] = fminf(smin[c][threadIdx.x], smin[c][threadIdx.x + s]);
                smax[c][threadIdx.x] = fmaxf(smax[c][threadIdx.x], smax[c][threadIdx.x + s]);
            }
        }
        __syncthreads();
    }
    if (threadIdx.x == 0) {
        float* p = part + ((size_t)ch * NBB + bb) * 6;
#pragma unroll
        for (int c = 0; c < 3; c++) { p[c] = smin[c][0]; p[3 + c] = smax[c][0]; }
    }
}

// ---------------- normalize + transpose-in (bbox combine folded in) ----------------
// Each block redoes the 16-partial combine (96 broadcast loads, trivial);
// identical fminf/fmaxf order to the old bbox2 -> bit-identical csz/isz.
__global__ __launch_bounds__(256) void k_normT(const float* __restrict__ lh,
                                               const float* __restrict__ rh,
                                               const float* __restrict__ part,
                                               const int* __restrict__ newid,
                                               float4* __restrict__ v4,
                                               float* __restrict__ csz) {
    int ch = blockIdx.x, bb = blockIdx.y;
    const float* src = (bb < BATCH) ? (lh + (size_t)bb * NV * 3)
                                    : (rh + (size_t)(bb - BATCH) * NV * 3);
    float mn[3] = {1e30f, 1e30f, 1e30f}, mx[3] = {-1e30f, -1e30f, -1e30f};
    for (int c2 = 0; c2 < NCHUNK; c2++) {
        const float* p = part + ((size_t)c2 * NBB + bb) * 6;
#pragma unroll
        for (int c = 0; c < 3; c++) {
            mn[c] = fminf(mn[c], p[c]);
            mx[c] = fmaxf(mx[c], p[3 + c]);
        }
    }
    float ctr[3], isz[3];
#pragma unroll
    for (int c = 0; c < 3; c++) {
        ctr[c] = 0.5f * (mn[c] + mx[c]);
        isz[c] = 1.f / (mx[c] - ctr[c]);
    }
    if (ch == 0 && threadIdx.x == 0) {       // csz needed by the fused last-step output
#pragma unroll
        for (int c = 0; c < 3; c++) {
            csz[c * NBB + bb] = ctr[c];
            csz[(3 + c) * NBB + bb] = mx[c] - ctr[c];
        }
    }
    int lo = ch * CHSZ, hi = min(lo + CHSZ, NV);
    for (int i = lo + threadIdx.x; i < hi; i += 256) {
        float4 o;
        o.x = (src[i * 3 + 0] - ctr[0]) * isz[0];
        o.y = (src[i * 3 + 1] - ctr[1]) * isz[1];
        o.z = (src[i * 3 + 2] - ctr[2]) * isz[2];
        o.w = 0.f;                               // sulc lives in v.w
        v4[(size_t)newid[i] * NBB + bb] = o;
    }
}

// ---------------- per-step: geometry -> featH = fp16x8 {n, 0.5*lap} ----------------
__global__ __launch_bounds__(256) void k_geom(const float4* __restrict__ v4,
                                              const int* __restrict__ adjB8,
                                              const int* __restrict__ adjC8,
                                              float4* __restrict__ featH) {
    int lane = threadIdx.x & 63;
    int blk = swz(blockIdx.x, gridDim.x);
    int vi = rfl(blk * 4 + (threadIdx.x >> 6));
    if (vi >= NV) return;
    float sgn = (lane < BATCH) ? 1.f : -1.f;   // rh: reversed winding flips face normals
    int4 blo = *(const int4*)&adjB8[(size_t)vi * 8];
    int4 bhi = *(const int4*)&adjB8[(size_t)vi * 8 + 4];
    int4 clo = *(const int4*)&adjC8[(size_t)vi * 8];
    int4 chi = *(const int4*)&adjC8[(size_t)vi * 8 + 4];
    int d = rfl(bhi.z);
    int ib[6] = {rfl(blo.x), rfl(blo.y), rfl(blo.z), rfl(blo.w), rfl(bhi.x), rfl(bhi.y)};
    int ic[6] = {rfl(clo.x), rfl(clo.y), rfl(clo.z), rfl(clo.w), rfl(chi.x), rfl(chi.y)};
    float4 a = v4[(size_t)vi * NBB + lane];
    float vnx = 0.f, vny = 0.f, vnz = 0.f, lx = 0.f, ly = 0.f, lz = 0.f;

    auto acc = [&](float4 b, float4 c) {
        float e1x = b.x - a.x, e1y = b.y - a.y, e1z = b.z - a.z;   // B - A
        float e2x = c.x - a.x, e2y = c.y - a.y, e2z = c.z - a.z;   // C - A
        float fnx = e1y * e2z - e1z * e2y;                         // face normal
        float fny = e1z * e2x - e1x * e2z;
        float fnz = e1x * e2y - e1y * e2x;
        vnx += fnx; vny += fny; vnz += fnz;
        float rd = 1.f / (sqrtf(fnx * fnx + fny * fny + fnz * fnz) + EPSV);
        float ux = c.x - b.x, uy = c.y - b.y, uz = c.z - b.z;
        float wx = a.x - b.x, wy = a.y - b.y, wz = a.z - b.z;
        float cB = (ux * wx + uy * wy + uz * wz) * rd;             // cot at B
        float rx = a.x - c.x, ry = a.y - c.y, rz = a.z - c.z;
        float sx = b.x - c.x, sy = b.y - c.y, sz2 = b.z - c.z;
        float cC = (rx * sx + ry * sy + rz * sz2) * rd;            // cot at C
        lx += cC * e1x + cB * e2x;
        ly += cC * e1y + cB * e2y;
        lz += cC * e1z + cB * e2z;
    };

    if (d == 6) {
#pragma unroll
        for (int g = 0; g < 2; g++) {
            float4 pb[3], pc[3];
#pragma unroll
            for (int k = 0; k < 3; k++) {
                pb[k] = v4[(size_t)ib[g * 3 + k] * NBB + lane];
                pc[k] = v4[(size_t)ic[g * 3 + k] * NBB + lane];
            }
#pragma unroll
            for (int k = 0; k < 3; k++) acc(pb[k], pc[k]);
        }
    } else {
#pragma unroll
        for (int k = 0; k < 6; k++)
            if (k < d) acc(v4[(size_t)ib[k] * NBB + lane], v4[(size_t)ic[k] * NBB + lane]);
    }
    vnx *= sgn; vny *= sgn; vnz *= sgn;
    float nn = 1.f / (sqrtf(vnx * vnx + vny * vny + vnz * vnz) + EPSV);
    float nl[8] = {vnx * nn, vny * nn, vnz * nn, 0.5f * lx, 0.5f * ly, 0.5f * lz, 0.f, 0.f};
    featH[(size_t)vi * NBB + lane] = pack8(nl);
}

// packed-pair accumulate helpers: same element order as the old unpack-to-array
// then add (bit-identical), but no 16-float staging array -> fewer VGPRs
__device__ __forceinline__ void addpk6(float4 g, float* m3) {   // 6 chans -> m3[0..5]
    HF4 u; u.f4 = g;
    float2 f0 = __half22float2(u.h2[0]); m3[0] += f0.x; m3[1] += f0.y;
    float2 f1 = __half22float2(u.h2[1]); m3[2] += f1.x; m3[3] += f1.y;
    float2 f2 = __half22float2(u.h2[2]); m3[4] += f2.x; m3[5] += f2.y;
}
__device__ __forceinline__ void addpk8(float4 g, float* m8) {   // 8 chans -> m8[0..7]
    HF4 u; u.f4 = g;
#pragma unroll
    for (int i = 0; i < 4; i++) {
        float2 f = __half22float2(u.h2[i]);
        m8[2 * i] += f.x; m8[2 * i + 1] += f.y;
    }
}

// ---------------- per-step: layer1  h = relu(feat@W1s + mean_nbr(feat)@W1n + b1) ----------------
__global__ __launch_bounds__(256) void k_layer1(const float4* __restrict__ v4,
                                                const float4* __restrict__ featH,
                                                const int* __restrict__ adjB8,
                                                const float* __restrict__ W1s,
                                                const float* __restrict__ W1n,
                                                const float* __restrict__ b1,
                                                float4* __restrict__ h4) {
    __shared__ float sWs[144], sWn[144], sb[16];
    int t = threadIdx.x;
    if (t < 144) { sWs[t] = W1s[t]; sWn[t] = W1n[t]; }
    if (t < 16) sb[t] = b1[t];
    __syncthreads();
    int lane = t & 63;
    int blk = swz(blockIdx.x, gridDim.x);
    int vi = rfl(blk * 4 + (t >> 6));
    if (vi >= NV) return;
    int4 blo = *(const int4*)&adjB8[(size_t)vi * 8];
    int4 bhi = *(const int4*)&adjB8[(size_t)vi * 8 + 4];
    int d = rfl(bhi.z);
    int ib[6] = {rfl(blo.x), rfl(blo.y), rfl(blo.z), rfl(blo.w), rfl(bhi.x), rfl(bhi.y)};
    float4 ov  = v4[(size_t)vi * NBB + lane];
    float4 onl = featH[(size_t)vi * NBB + lane];
    float m[9] = {0.f, 0.f, 0.f, 0.f, 0.f, 0.f, 0.f, 0.f, 0.f};
    if (d == 6) {
#pragma unroll
        for (int g = 0; g < 2; g++) {
            float4 gv[3], gn[3];
#pragma unroll
            for (int k = 0; k < 3; k++) {
                gv[k] = v4[(size_t)ib[g * 3 + k] * NBB + lane];
                gn[k] = featH[(size_t)ib[g * 3 + k] * NBB + lane];
            }
#pragma unroll
            for (int k = 0; k < 3; k++) {
                m[0] += gv[k].x; m[1] += gv[k].y; m[2] += gv[k].z;
                addpk6(gn[k], m + 3);
            }
        }
    } else {
#pragma unroll
        for (int k = 0; k < 6; k++)
            if (k < d) {
                float4 gv = v4[(size_t)ib[k] * NBB + lane];
                float4 gn = featH[(size_t)ib[k] * NBB + lane];
                m[0] += gv.x; m[1] += gv.y; m[2] += gv.z;
                addpk6(gn, m + 3);
            }
    }
    float nl[8];
    unpack8(onl, nl);
    float own[9] = {ov.x, ov.y, ov.z, nl[0], nl[1], nl[2], nl[3], nl[4], nl[5]};
    float inv = 1.f / (float)d;
#pragma unroll
    for (int i = 0; i < 9; i++) m[i] *= inv;
    HF4 h0, h1;
#pragma unroll
    for (int jp = 0; jp < 8; jp++) {         // channel pairs -> pack directly
        float a0 = sb[2 * jp], a1 = sb[2 * jp + 1];
#pragma unroll
        for (int i = 0; i < 9; i++) {
            a0 += own[i] * sWs[i * 16 + 2 * jp]     + m[i] * sWn[i * 16 + 2 * jp];
            a1 += own[i] * sWs[i * 16 + 2 * jp + 1] + m[i] * sWn[i * 16 + 2 * jp + 1];
        }
        __half2 p = __floats2half2_rn(fmaxf(a0, 0.f), fmaxf(a1, 0.f));
        if (jp < 4) h0.h2[jp] = p; else h1.h2[jp - 4] = p;
    }
    float4* hp = h4 + (size_t)vi * 2 * NBB + lane;
    hp[0 * NBB] = h0.f4;
    hp[1 * NBB] = h1.f4;
}

// ---------------- per-step: layer2 + output head + state update (sulc in v.w) ----------------
// LAST=true (final step only): also writes the (2,B,V,4) output directly from
// the freshly computed vv — identical values to what k_out read back from v4.
template<bool LAST>
__global__ __launch_bounds__(256) void k_layer2(const float4* __restrict__ h4,
                                                const float4* __restrict__ featH,
                                                const int* __restrict__ adjB8,
                                                const float* __restrict__ W2s,
                                                const float* __restrict__ W2n,
                                                const float* __restrict__ b2,
                                                const float* __restrict__ Wo,
                                                const float* __restrict__ bo,
                                                float4* __restrict__ v4,
                                                const float* __restrict__ csz,
                                                const int* __restrict__ order,
                                                float4* __restrict__ out) {
    __shared__ float sWs[256], sWn[256], sb[16], sWo[48], sbo[3];
    int t = threadIdx.x;
    sWs[t] = W2s[t];
    sWn[t] = W2n[t];
    if (t < 16) sb[t] = b2[t];
    if (t < 48) sWo[t] = Wo[t];
    if (t < 3) sbo[t] = bo[t];
    __syncthreads();
    int lane = t & 63;
    int blk = swz(blockIdx.x, gridDim.x);
    int vi = rfl(blk * 4 + (t >> 6));
    if (vi >= NV) return;
    int4 blo = *(const int4*)&adjB8[(size_t)vi * 8];
    int4 bhi = *(const int4*)&adjB8[(size_t)vi * 8 + 4];
    int d = rfl(bhi.z);
    int ib[6] = {rfl(blo.x), rfl(blo.y), rfl(blo.z), rfl(blo.w), rfl(bhi.x), rfl(bhi.y)};
    // epilogue operands issued early (consumed last)
    float4 fnl = featH[(size_t)vi * NBB + lane];   // this step's normal
    float4 vv = v4[(size_t)vi * NBB + lane];
    const float4* ho = h4 + (size_t)vi * 2 * NBB + lane;
    float4 oA = ho[0 * NBB], oB = ho[1 * NBB];
    float m[16];
#pragma unroll
    for (int i = 0; i < 16; i++) m[i] = 0.f;
    if (d == 6) {
#pragma unroll
        for (int g = 0; g < 2; g++) {
            float4 gA[3], gB[3];
#pragma unroll
            for (int k = 0; k < 3; k++) {    // 3 neighbors (6 float4) in flight
                const float4* hu = h4 + (size_t)ib[g * 3 + k] * 2 * NBB + lane;
                gA[k] = hu[0 * NBB]; gB[k] = hu[1 * NBB];
            }
#pragma unroll
            for (int k = 0; k < 3; k++) {
                addpk8(gA[k], m);
                addpk8(gB[k], m + 8);
            }
        }
    } else {
#pragma unroll
        for (int k = 0; k < 6; k++)
            if (k < d) {
                const float4* hu = h4 + (size_t)ib[k] * 2 * NBB + lane;
                addpk8(hu[0 * NBB], m);
                addpk8(hu[1 * NBB], m + 8);
            }
    }
    float own[16];
    unpack8(oA, own); unpack8(oB, own + 8);
    float inv = 1.f / (float)d;
#pragma unroll
    for (int i = 0; i < 16; i++) m[i] *= inv;
    float dv[3] = {sbo[0], sbo[1], sbo[2]};
#pragma unroll
    for (int j = 0; j < 16; j++) {           // output head folded in: no h2[16]
        float acc = sb[j];
#pragma unroll
        for (int i = 0; i < 16; i++) acc += own[i] * sWs[i * 16 + j] + m[i] * sWn[i * 16 + j];
        acc = fmaxf(acc, 0.f);
        dv[0] += acc * sWo[j * 3 + 0];
        dv[1] += acc * sWo[j * 3 + 1];
        dv[2] += acc * sWo[j * 3 + 2];
    }
    float nlo[8];
    unpack8(fnl, nlo);                       // nlo[0..2] = this step's normal
    vv.x += STEPSZ * dv[0];
    vv.y += STEPSZ * dv[1];
    vv.z += STEPSZ * dv[2];
    vv.w += STEPSZ * (nlo[0] * dv[0] + nlo[1] * dv[1] + nlo[2] * dv[2]);
    v4[(size_t)vi * NBB + lane] = vv;
    if (LAST) {
        int orig = rfl(order[vi]);           // NEW -> ORIGINAL vertex id
        float4 r;
        r.x = vv.x * csz[(3 + 0) * NBB + lane];
        r.y = vv.y * csz[(3 + 1) * NBB + lane];
        r.z = vv.z * csz[(3 + 2) * NBB + lane];
        r.w = vv.w;
        out[(size_t)lane * NV + orig] = r;   // lane = hemi*32 + b matches (2,B,V,4)
    }
}

extern "C" void kernel_launch(void* const* d_in, const int* in_sizes, int n_in,
                              void* d_out, int out_size, void* d_ws, size_t ws_size,
                              hipStream_t stream) {
    const float* lh  = (const float*)d_in[0];
    const float* rh  = (const float*)d_in[1];
    const float* W1s = (const float*)d_in[2];
    const float* W1n = (const float*)d_in[3];
    const float* b1  = (const float*)d_in[4];
    const float* W2s = (const float*)d_in[5];
    const float* W2n = (const float*)d_in[6];
    const float* b2  = (const float*)d_in[7];
    const float* Wo  = (const float*)d_in[8];
    const float* bo  = (const float*)d_in[9];
    const int* faces = (const int*)d_in[10];

    float* ws    = (float*)d_ws;
    float4* v4   = (float4*)(ws + OFF_V);
    float4* ftH  = (float4*)(ws + OFF_FEAT);
    float4* h4   = (float4*)(ws + OFF_H);
    float* part  = ws + OFF_H;                // bbox partials borrow h's space pre-loop
    float* csz   = ws + OFF_CSZ;
    int* ibase   = (int*)(ws + OFF_INT);
    int* deg     = ibase;
    int* nbrB    = ibase + (size_t)NV;
    int* nbrC    = ibase + (size_t)7 * NV;
    int* newid   = ibase + (size_t)13 * NV;
    int* order   = ibase + (size_t)14 * NV;
    int* adjB8   = ibase + (size_t)16 * NV;   // 16*NV ints from 16B-aligned base -> aligned
    int* adjC8   = ibase + (size_t)24 * NV;

    build_perm_host();                        // once per process, pure combinatorics
    hipMemcpyAsync(newid, g_newid, NV * sizeof(int), hipMemcpyHostToDevice, stream);
    hipMemcpyAsync(order, g_order, NV * sizeof(int), hipMemcpyHostToDevice, stream);

    const int WPB = 4;                        // waves (vertices) per block
    dim3 gv((NV + WPB - 1) / WPB);            // 2561 blocks, wave-per-vertex

    k_zero<<<(NV + 255) / 256, 256, 0, stream>>>(deg, NV);
    k_build<<<(NF + 255) / 256, 256, 0, stream>>>(faces, deg, nbrB, nbrC);
    k_remap<<<(NV + 255) / 256, 256, 0, stream>>>(deg, nbrB, nbrC, newid, order, adjB8, adjC8);
    k_bbox1<<<dim3(NCHUNK, NBB), 256, 0, stream>>>(lh, rh, part);
    k_normT<<<dim3(NCHUNK, NBB), 256, 0, stream>>>(lh, rh, part, newid, v4, csz);

    for (int s = 0; s < NSTEPS; s++) {
        k_geom<<<gv, 256, 0, stream>>>(v4, adjB8, adjC8, ftH);
        k_layer1<<<gv, 256, 0, stream>>>(v4, ftH, adjB8, W1s, W1n, b1, h4);
        if (s < NSTEPS - 1)
            k_layer2<false><<<gv, 256, 0, stream>>>(h4, ftH, adjB8, W2s, W2n, b2, Wo, bo,
                                                    v4, csz, order, (float4*)d_out);
        else
            k_layer2<true><<<gv, 256, 0, stream>>>(h4, ftH, adjB8, W2s, W2n, b2, Wo, bo,
                                                   v4, csz, order, (float4*)d_out);
    }
}